// Round 2
// baseline (9617.171 us; speedup 1.0000x reference)
//
#include <hip/hip_runtime.h>
#include <math.h>

typedef __bf16 bf16;
typedef __bf16 bf16x8 __attribute__((ext_vector_type(8)));
typedef __bf16 bf16x4 __attribute__((ext_vector_type(4)));
typedef float  f32x4  __attribute__((ext_vector_type(4)));

#define TT 64
#define DD 768
#define MR 1024      // B*T = 16*64
#define ALPHAF 0.4f
#define NWG 64       // persistent scan workgroups

__device__ __forceinline__ float geluf(float x){
  return 0.5f*x*(1.0f + erff(x*0.70710678118654752f));
}
__device__ __forceinline__ void split2(float v, bf16* hi, bf16* lo){
  bf16 h = (bf16)v; *hi = h; *lo = (bf16)(v - (float)h);
}

// ---------------- embedding ----------------
__global__ __launch_bounds__(256) void k_embed(const int* __restrict__ tok,
    const float* __restrict__ emb, const float* __restrict__ pos, float* __restrict__ x){
  int m = blockIdx.x; int t = m & 63; int id = tok[m];
  const float* e = emb + (size_t)id*DD;
  const float* p = pos + (size_t)t*DD;
  float* xr = x + (size_t)m*DD;
  for (int j = threadIdx.x; j < DD; j += 256) xr[j] = e[j] + p[j];
}

// ---------------- layernorm (+optional l2norm) ----------------
template<bool L2N>
__global__ __launch_bounds__(256) void k_ln(const float* __restrict__ in,
    const float* __restrict__ g, const float* __restrict__ b, float* __restrict__ out){
  __shared__ float red[8];
  int m = blockIdx.x, tid = threadIdx.x, lane = tid & 63, wid = tid >> 6;
  const float* x = in + (size_t)m*DD;
  float v[3]; float s = 0.f, ss = 0.f;
  #pragma unroll
  for (int j = 0; j < 3; j++){ float t0 = x[tid + j*256]; v[j] = t0; s += t0; ss += t0*t0; }
  #pragma unroll
  for (int o = 1; o < 64; o <<= 1){ s += __shfl_xor(s, o); ss += __shfl_xor(ss, o); }
  if (lane == 0){ red[wid] = s; red[4+wid] = ss; }
  __syncthreads();
  s  = red[0]+red[1]+red[2]+red[3];
  ss = red[4]+red[5]+red[6]+red[7];
  float mean = s*(1.f/768.f);
  float var  = ss*(1.f/768.f) - mean*mean;
  float rstd = rsqrtf(var + 1e-5f);
  float y[3];
  #pragma unroll
  for (int j = 0; j < 3; j++){ int n = tid + j*256; y[j] = (v[j]-mean)*rstd*g[n] + b[n]; }
  if (L2N){
    float n2 = y[0]*y[0] + y[1]*y[1] + y[2]*y[2];
    #pragma unroll
    for (int o = 1; o < 64; o <<= 1) n2 += __shfl_xor(n2, o);
    __syncthreads();
    if (lane == 0) red[wid] = n2;
    __syncthreads();
    n2 = red[0]+red[1]+red[2]+red[3];
    float inv = 1.f / fmaxf(sqrtf(n2), 1e-12f);
    y[0] *= inv; y[1] *= inv; y[2] *= inv;
  }
  float* o_ = out + (size_t)m*DD;
  #pragma unroll
  for (int j = 0; j < 3; j++) o_[tid + j*256] = y[j];
}

// ---------------- attention (one WG per (b,h)) ----------------
__global__ __launch_bounds__(256) void k_attn(const float* __restrict__ qkv, float* __restrict__ o){
  __shared__ float kv[64][96];
  __shared__ float sm[64][68];
  int bh = blockIdx.x; int b = bh >> 3, h = bh & 7;
  int tid = threadIdx.x;
  const float* base = qkv + (size_t)b*64*2304 + h*96;
  for (int idx = tid; idx < 64*96; idx += 256){ int i = idx/96, d = idx - i*96;
    kv[i][d] = base[(size_t)i*2304 + 768 + d]; }
  __syncthreads();
  {
    int i = tid >> 2;
    const float* q = base + (size_t)i*2304;
    int j0 = (tid & 3)*16;
    for (int jj = 0; jj < 16; jj++){
      int j = j0 + jj;
      float sv = -1e30f;
      if (j <= i){ float acc = 0.f;
        for (int d = 0; d < 96; d++) acc += q[d]*kv[j][d];
        sv = acc*0.10206207261596576f; }
      sm[i][j] = sv;
    }
  }
  __syncthreads();
  for (int idx = tid; idx < 64*96; idx += 256){ int i = idx/96, d = idx - i*96;
    kv[i][d] = base[(size_t)i*2304 + 1536 + d]; }
  if (tid < 64){
    int i = tid;
    float mx = -1e30f;
    for (int j = 0; j <= i; j++) mx = fmaxf(mx, sm[i][j]);
    float sum = 0.f;
    for (int j = 0; j <= i; j++){ float e = expf(sm[i][j]-mx); sm[i][j] = e; sum += e; }
    float inv = 1.f/sum;
    for (int j = 0; j <= i; j++) sm[i][j] *= inv;
  }
  __syncthreads();
  for (int idx = tid; idx < 64*96; idx += 256){
    int i = idx/96, d = idx - i*96;
    float acc = 0.f;
    for (int j = 0; j <= i; j++) acc += sm[i][j]*kv[j][d];
    o[(size_t)(b*64+i)*768 + h*96 + d] = acc;
  }
}

// ---------------- generic MFMA GEMM: out[M,N] = act(scale*A[M,K]@B[N,K]^T + bias) + res ----------------
// SPLIT: double-bf16 (hi+lo) 3-term product for ~fp32 accuracy.
template<bool SPLIT>
__global__ __launch_bounds__(256) void k_gemm(
    const float* __restrict__ A, int lda,
    const float* __restrict__ Bw, int ldb, int nrb,
    int M, int N, int K,
    const float* __restrict__ bias, const float* __restrict__ res,
    float* __restrict__ outF, bf16* __restrict__ outB,
    float scale, int act)
{
  __shared__ bf16 Ash[128][40];
  __shared__ bf16 Bsh[128][40];
  __shared__ bf16 Asl[SPLIT?128:1][40];
  __shared__ bf16 Bsl[SPLIT?128:1][40];
  int tid = threadIdx.x;
  int m0 = blockIdx.y*128, n0 = blockIdx.x*128;
  int lane = tid & 63, wid = tid >> 6;
  int wr = (wid >> 1)*64, wc = (wid & 1)*64;
  int l15 = lane & 15, kb = lane >> 4;
  f32x4 acc[4][4];
  #pragma unroll
  for (int i = 0; i < 4; i++)
    #pragma unroll
    for (int j = 0; j < 4; j++){ f32x4 z = {0.f,0.f,0.f,0.f}; acc[i][j] = z; }
  int rA = tid >> 3;          // 0..31
  int k4 = (tid & 7)*4;       // 0..28
  for (int kk = 0; kk < K; kk += 32){
    #pragma unroll
    for (int it = 0; it < 4; ++it){
      int r = it*32 + rA;
      float4 va = *(const float4*)(A + (size_t)(m0+r)*lda + kk + k4);
      bf16 h0,h1_,h2,h3,l0,l1,l2,l3;
      split2(va.x,&h0,&l0); split2(va.y,&h1_,&l1); split2(va.z,&h2,&l2); split2(va.w,&h3,&l3);
      *(bf16x4*)(&Ash[r][k4]) = (bf16x4){h0,h1_,h2,h3};
      if (SPLIT) *(bf16x4*)(&Asl[r][k4]) = (bf16x4){l0,l1,l2,l3};
      int rB = n0 + r;
      float4 vb;
      if (rB < nrb) vb = *(const float4*)(Bw + (size_t)rB*ldb + kk + k4);
      else { vb.x = 0.f; vb.y = 0.f; vb.z = 0.f; vb.w = 0.f; }
      split2(vb.x,&h0,&l0); split2(vb.y,&h1_,&l1); split2(vb.z,&h2,&l2); split2(vb.w,&h3,&l3);
      *(bf16x4*)(&Bsh[r][k4]) = (bf16x4){h0,h1_,h2,h3};
      if (SPLIT) *(bf16x4*)(&Bsl[r][k4]) = (bf16x4){l0,l1,l2,l3};
    }
    __syncthreads();
    bf16x8 ah[4], bh[4], al[4], bl[4];
    #pragma unroll
    for (int i = 0; i < 4; i++){ ah[i] = *(const bf16x8*)(&Ash[wr + i*16 + l15][kb*8]);
      if (SPLIT) al[i] = *(const bf16x8*)(&Asl[wr + i*16 + l15][kb*8]); }
    #pragma unroll
    for (int j = 0; j < 4; j++){ bh[j] = *(const bf16x8*)(&Bsh[wc + j*16 + l15][kb*8]);
      if (SPLIT) bl[j] = *(const bf16x8*)(&Bsl[wc + j*16 + l15][kb*8]); }
    #pragma unroll
    for (int i = 0; i < 4; i++)
      #pragma unroll
      for (int j = 0; j < 4; j++){
        acc[i][j] = __builtin_amdgcn_mfma_f32_16x16x32_bf16(ah[i], bh[j], acc[i][j], 0, 0, 0);
        if (SPLIT){
          acc[i][j] = __builtin_amdgcn_mfma_f32_16x16x32_bf16(ah[i], bl[j], acc[i][j], 0, 0, 0);
          acc[i][j] = __builtin_amdgcn_mfma_f32_16x16x32_bf16(al[i], bh[j], acc[i][j], 0, 0, 0);
        }
      }
    __syncthreads();
  }
  #pragma unroll
  for (int i = 0; i < 4; i++){
    #pragma unroll
    for (int j = 0; j < 4; j++){
      #pragma unroll
      for (int r = 0; r < 4; r++){
        int m = m0 + wr + i*16 + kb*4 + r;
        int n = n0 + wc + j*16 + l15;
        if (n < N){
          float v = acc[i][j][r]*scale;
          if (bias) v += bias[n];
          if (act == 1) v = geluf(v);
          if (res) v += res[(size_t)m*N + n];
          size_t off = (size_t)m*N + n;
          if (outF) outF[off] = v;
          if (outB) outB[off] = (bf16)v;
        }
      }
    }
  }
}

// ---------------- transpose / split helpers ----------------
__global__ __launch_bounds__(256) void k_transpose_f(const float* __restrict__ in, float* __restrict__ out, int R, int C){
  __shared__ float tile[32][33];
  int r0 = blockIdx.y*32, c0 = blockIdx.x*32;
  int tx = threadIdx.x & 31, ty = threadIdx.x >> 5;
  #pragma unroll
  for (int i = 0; i < 32; i += 8) tile[ty+i][tx] = in[(size_t)(r0+ty+i)*C + (c0+tx)];
  __syncthreads();
  #pragma unroll
  for (int i = 0; i < 32; i += 8) out[(size_t)(c0+ty+i)*R + (r0+tx)] = tile[tx][ty+i];
}

__global__ __launch_bounds__(256) void k_transpose_split(const float* __restrict__ in,
    bf16* __restrict__ hi, bf16* __restrict__ lo, int R, int C){
  __shared__ float tile[32][33];
  int r0 = blockIdx.y*32, c0 = blockIdx.x*32;
  int tx = threadIdx.x & 31, ty = threadIdx.x >> 5;
  #pragma unroll
  for (int i = 0; i < 32; i += 8) tile[ty+i][tx] = in[(size_t)(r0+ty+i)*C + (c0+tx)];
  __syncthreads();
  #pragma unroll
  for (int i = 0; i < 32; i += 8){
    size_t off = (size_t)(c0+ty+i)*R + (r0+tx);
    split2(tile[tx][ty+i], hi+off, lo+off);
  }
}

__global__ __launch_bounds__(256) void k_split(const float* __restrict__ in,
    bf16* __restrict__ hi, bf16* __restrict__ lo, int n){
  int i = blockIdx.x*256 + threadIdx.x;
  if (i < n) split2(in[i], hi+i, lo+i);
}

__global__ __launch_bounds__(256) void k_bdg(const float* __restrict__ gw, const float* __restrict__ cpb2, float* __restrict__ bdg){
  int g = blockIdx.x*256 + threadIdx.x;
  if (g < 768){
    const float* row = gw + (size_t)g*1536 + 768;
    float s = 0.f;
    for (int j = 0; j < 768; j++) s += cpb2[j]*row[j];
    bdg[g] = s;
  }
}

__global__ void k_init(int* cnt){ if (threadIdx.x < 64) cnt[threadIdx.x] = 0; }

// ---------------- persistent scan ----------------
__device__ __forceinline__ f32x4 dot16s(const bf16* __restrict__ ah, const bf16* __restrict__ al,
                                        const bf16* __restrict__ bh, const bf16* __restrict__ bl, int K){
  f32x4 a0 = {0.f,0.f,0.f,0.f}, a1 = {0.f,0.f,0.f,0.f};
  #pragma unroll 2
  for (int kk = 0; kk < K; kk += 32){
    bf16x8 vah = *(const bf16x8*)(ah+kk), val_ = *(const bf16x8*)(al+kk);
    bf16x8 vbh = *(const bf16x8*)(bh+kk), vbl  = *(const bf16x8*)(bl+kk);
    a0 = __builtin_amdgcn_mfma_f32_16x16x32_bf16(vah, vbh, a0, 0,0,0);
    a1 = __builtin_amdgcn_mfma_f32_16x16x32_bf16(vah, vbl, a1, 0,0,0);
    a1 = __builtin_amdgcn_mfma_f32_16x16x32_bf16(val_, vbh, a1, 0,0,0);
  }
  return a0 + a1;
}

__device__ __forceinline__ void gbar(int* cnt, int ep){
  __syncthreads();
  if (threadIdx.x == 0){
    __threadfence();
    __hip_atomic_fetch_add(cnt, 1, __ATOMIC_RELEASE, __HIP_MEMORY_SCOPE_AGENT);
    while (__hip_atomic_load(cnt, __ATOMIC_RELAXED, __HIP_MEMORY_SCOPE_AGENT) < NWG*ep)
      __builtin_amdgcn_s_sleep(2);
    __threadfence();
  }
  __syncthreads();
}

__global__ __launch_bounds__(256) void k_scan(
  const bf16* __restrict__ WAh, const bf16* __restrict__ WAl,
  const bf16* __restrict__ V1th, const bf16* __restrict__ V1tl,
  const bf16* __restrict__ Wc1h, const bf16* __restrict__ Wc1l,
  const bf16* __restrict__ WDh, const bf16* __restrict__ WDl,
  const float* __restrict__ ctxV0b, const float* __restrict__ gctx,
  const float* __restrict__ ctx,
  const float* __restrict__ b1, const float* __restrict__ cpb1,
  const float* __restrict__ cpb2, const float* __restrict__ bdg,
  const float* __restrict__ gateb, const float* __restrict__ outg, const float* __restrict__ outb,
  float* __restrict__ hall,
  bf16* __restrict__ hbh, bf16* __restrict__ hbl,
  bf16* __restrict__ h1h, bf16* __restrict__ h1l,
  float* __restrict__ c1, bf16* __restrict__ c1h, bf16* __restrict__ c1l,
  bf16* __restrict__ gcah, bf16* __restrict__ gcal,
  float* __restrict__ cf, float* __restrict__ gpre,
  float* __restrict__ tfs, int* cnt)
{
  __shared__ float red[8];
  const int tid = threadIdx.x, lane = tid & 63, wid = tid >> 6;
  const int W = blockIdx.x*4 + wid;
  const int l15 = lane & 15, kb = lane >> 4;
  int ep = 0;
  for (int t = 0; t < TT; ++t){
    // ---- stage A: [16,3840] = h @ [a*RV0 | a*R@temp_w^T]^T
    if (W < 240){
      int n0 = W*16;
      f32x4 a = {0.f,0.f,0.f,0.f};
      if (t > 0){
        size_t aoff = ((size_t)l15*TT + (t-1))*DD + kb*8;
        size_t boff = (size_t)(n0 + l15)*DD + kb*8;
        a = dot16s(hbh + aoff, hbl + aoff, WAh + boff, WAl + boff, 768);
      }
      #pragma unroll
      for (int r = 0; r < 4; r++){
        int m = kb*4 + r, n = n0 + l15;
        float v = a[r];
        if (n < 3072){
          float hv = geluf(v + ctxV0b[((size_t)m*TT + t)*3072 + n]);
          split2(hv, h1h + m*3072 + n, h1l + m*3072 + n);
        } else tfs[m*DD + (n - 3072)] = v;
      }
    }
    gbar(cnt, ++ep);
    // ---- stage B: c1 = gelu(h1 @ V1 + b1)
    if (W < 48){
      int n0 = W*16;
      size_t aoff = (size_t)l15*3072 + kb*8;
      size_t boff = (size_t)(n0 + l15)*3072 + kb*8;
      f32x4 a = dot16s(h1h + aoff, h1l + aoff, V1th + boff, V1tl + boff, 3072);
      #pragma unroll
      for (int r = 0; r < 4; r++){
        int m = kb*4 + r, n = n0 + l15;
        float v = geluf(a[r] + b1[n]);
        c1[m*DD + n] = v;
        split2(v, c1h + m*DD + n, c1l + m*DD + n);
      }
    }
    gbar(cnt, ++ep);
    // ---- stage C: gca = gelu(l2norm(c1) @ cp_w1^T + cp_b1)
    if (W < 48){
      const float* cp = c1 + (size_t)l15*DD + kb*192;
      float s = 0.f;
      #pragma unroll 8
      for (int i = 0; i < 192; i += 4){ float4 q = *(const float4*)(cp + i);
        s += q.x*q.x + q.y*q.y + q.z*q.z + q.w*q.w; }
      s += __shfl_xor(s, 16); s += __shfl_xor(s, 32);
      float inv = 1.f / fmaxf(sqrtf(s), 1e-12f);
      int n0 = W*16;
      size_t aoff = (size_t)l15*DD + kb*8;
      size_t boff = (size_t)(n0 + l15)*DD + kb*8;
      f32x4 a = dot16s(c1h + aoff, c1l + aoff, Wc1h + boff, Wc1l + boff, 768);
      #pragma unroll
      for (int r = 0; r < 4; r++){
        int m = kb*4 + r, n = n0 + l15;
        float invm = __shfl(inv, m);
        float v = geluf(a[r]*invm + cpb1[n]);
        split2(v, gcah + m*DD + n, gcal + m*DD + n);
      }
    }
    gbar(cnt, ++ep);
    // ---- stage D: [cf | gate_pre_cf] = gca @ [cp_w2 | Wdg]^T
    if (W < 96){
      int n0 = W*16;
      size_t aoff = (size_t)l15*DD + kb*8;
      size_t boff = (size_t)(n0 + l15)*DD + kb*8;
      f32x4 a = dot16s(gcah + aoff, gcal + aoff, WDh + boff, WDl + boff, 768);
      #pragma unroll
      for (int r = 0; r < 4; r++){
        int m = kb*4 + r, n = n0 + l15;
        if (n < 768) cf[m*DD + n] = a[r] + cpb2[n];
        else         gpre[m*DD + (n - 768)] = a[r] + bdg[n - 768];
      }
    }
    gbar(cnt, ++ep);
    // ---- combine: gate, h_t = clip(LN(...))
    if (blockIdx.x < 16){
      int m = blockIdx.x;
      size_t bidx = ((size_t)m*TT + t)*DD;
      float vals[3]; float s = 0.f, ss = 0.f;
      #pragma unroll
      for (int j = 0; j < 3; j++){
        int n = tid + j*256;
        float gi = gctx[bidx + n] + gpre[m*DD + n] + gateb[n];
        float gate = 1.f/(1.f + expf(-gi));
        float val = gate*(cf[m*DD + n] + tfs[m*DD + n]) + (1.f - gate)*ctx[bidx + n];
        vals[j] = val; s += val; ss += val*val;
      }
      #pragma unroll
      for (int o = 1; o < 64; o <<= 1){ s += __shfl_xor(s, o); ss += __shfl_xor(ss, o); }
      if (lane == 0){ red[wid] = s; red[4+wid] = ss; }
      __syncthreads();
      s  = red[0]+red[1]+red[2]+red[3];
      ss = red[4]+red[5]+red[6]+red[7];
      float mean = s*(1.f/768.f), var = ss*(1.f/768.f) - mean*mean;
      float rstd = rsqrtf(var + 1e-5f);
      #pragma unroll
      for (int j = 0; j < 3; j++){
        int n = tid + j*256;
        float y = (vals[j]-mean)*rstd*outg[n] + outb[n];
        y = fminf(5.f, fmaxf(-5.f, y));
        hall[bidx + n] = y;
        split2(y, hbh + bidx + n, hbl + bidx + n);
      }
    }
    gbar(cnt, ++ep);
  }
}

// ---------------- host ----------------
static inline void gemmT(hipStream_t s, bool split, const float* A, int lda, const float* Bw, int ldb, int nrb,
                        int M, int N, int K, const float* bias, const float* res,
                        float* outF, bf16* outB, float scale, int act){
  dim3 g((N + 127)/128, M/128);
  if (split) k_gemm<true><<<g, 256, 0, s>>>(A, lda, Bw, ldb, nrb, M, N, K, bias, res, outF, outB, scale, act);
  else       k_gemm<false><<<g, 256, 0, s>>>(A, lda, Bw, ldb, nrb, M, N, K, bias, res, outF, outB, scale, act);
}

extern "C" void kernel_launch(void* const* d_in, const int* in_sizes, int n_in,
                              void* d_out, int out_size, void* d_ws, size_t ws_size,
                              hipStream_t stream)
{
  (void)in_sizes; (void)n_in; (void)out_size; (void)ws_size;
  const int*   tok = (const int*)d_in[0];
  const float* emb = (const float*)d_in[1];
  const float* pos = (const float*)d_in[2];
  const float* aiw = (const float*)d_in[3];
  const float* aib = (const float*)d_in[4];
  const float* aow = (const float*)d_in[5];
  const float* aob = (const float*)d_in[6];
  const float* fw1 = (const float*)d_in[7];
  const float* fb1 = (const float*)d_in[8];
  const float* fw2 = (const float*)d_in[9];
  const float* fb2 = (const float*)d_in[10];
  const float* n1g = (const float*)d_in[11];
  const float* n1b = (const float*)d_in[12];
  const float* n2g = (const float*)d_in[13];
  const float* n2b = (const float*)d_in[14];
  const float* eng = (const float*)d_in[15];
  const float* enb = (const float*)d_in[16];
  const float* V0  = (const float*)d_in[17];
  const float* b0  = (const float*)d_in[18];
  const float* V1  = (const float*)d_in[19];
  const float* b1  = (const float*)d_in[20];
  const float* cw1 = (const float*)d_in[21];
  const float* cb1 = (const float*)d_in[22];
  const float* cw2 = (const float*)d_in[23];
  const float* cb2 = (const float*)d_in[24];
  const float* gw  = (const float*)d_in[25];
  const float* gb  = (const float*)d_in[26];
  const float* tw  = (const float*)d_in[27];
  const float* Rm  = (const float*)d_in[28];
  const float* og  = (const float*)d_in[29];
  const float* ob  = (const float*)d_in[30];
  const float* lmw = (const float*)d_in[31];
  float* out = (float*)d_out;

  char* base = (char*)d_ws; size_t off = 0;
  auto alloc = [&](size_t bytes)->void*{
    off = (off + 255) & ~(size_t)255; void* p = base + off; off += bytes; return p; };

  float* x     = (float*)alloc((size_t)MR*DD*4);
  float* xn    = (float*)alloc((size_t)MR*DD*4);
  float* qkv   = (float*)alloc((size_t)MR*2304*4);
  float* o_    = (float*)alloc((size_t)MR*DD*4);
  float* mid   = (float*)alloc((size_t)MR*2048*4);
  float* ctx   = (float*)alloc((size_t)MR*DD*4);
  float* V0t   = (float*)alloc((size_t)3072*768*4);
  float* cw2t  = (float*)alloc((size_t)768*768*4);
  float* ctxV0 = (float*)alloc((size_t)MR*3072*4);
  float* gctx  = (float*)alloc((size_t)MR*DD*4);
  float* hall  = (float*)alloc((size_t)MR*DD*4);
  float* WAf   = (float*)alloc((size_t)3840*768*4);
  float* WDg   = (float*)alloc((size_t)768*768*4);
  float* bdg   = (float*)alloc(768*4);
  bf16*  WAh   = (bf16*)alloc((size_t)3840*768*2);
  bf16*  WAl   = (bf16*)alloc((size_t)3840*768*2);
  bf16*  V1th  = (bf16*)alloc((size_t)768*3072*2);
  bf16*  V1tl  = (bf16*)alloc((size_t)768*3072*2);
  bf16*  Wc1h  = (bf16*)alloc((size_t)768*768*2);
  bf16*  Wc1l  = (bf16*)alloc((size_t)768*768*2);
  bf16*  WDh   = (bf16*)alloc((size_t)1536*768*2);
  bf16*  WDl   = (bf16*)alloc((size_t)1536*768*2);
  bf16*  hbh   = (bf16*)alloc((size_t)MR*DD*2);
  bf16*  hbl   = (bf16*)alloc((size_t)MR*DD*2);
  bf16*  h1h   = (bf16*)alloc((size_t)16*3072*2);
  bf16*  h1l   = (bf16*)alloc((size_t)16*3072*2);
  float* c1    = (float*)alloc((size_t)16*768*4);
  bf16*  c1h   = (bf16*)alloc((size_t)16*768*2);
  bf16*  c1l   = (bf16*)alloc((size_t)16*768*2);
  bf16*  gcah  = (bf16*)alloc((size_t)16*768*2);
  bf16*  gcal  = (bf16*)alloc((size_t)16*768*2);
  float* cf    = (float*)alloc((size_t)16*768*4);
  float* gpre  = (float*)alloc((size_t)16*768*4);
  float* tfs   = (float*)alloc((size_t)16*768*4);
  int*   cnt   = (int*)alloc(256);

  // ----- encoder -----
  k_embed<<<MR, 256, 0, stream>>>(tok, emb, pos, x);
  for (int l = 0; l < 2; l++){
    k_ln<false><<<MR, 256, 0, stream>>>(x, n1g + l*768, n1b + l*768, xn);
    gemmT(stream, true, xn, 768, aiw + (size_t)l*2304*768, 768, 2304, MR, 2304, 768,
         aib + l*2304, nullptr, qkv, nullptr, 1.f, 0);
    k_attn<<<128, 256, 0, stream>>>(qkv, o_);
    gemmT(stream, true, o_, 768, aow + (size_t)l*768*768, 768, 768, MR, 768, 768,
         aob + l*768, x, x, nullptr, 1.f, 0);
    k_ln<false><<<MR, 256, 0, stream>>>(x, n2g + l*768, n2b + l*768, xn);
    gemmT(stream, true, xn, 768, fw1 + (size_t)l*2048*768, 768, 2048, MR, 2048, 768,
         fb1 + l*2048, nullptr, mid, nullptr, 1.f, 1);
    gemmT(stream, true, mid, 2048, fw2 + (size_t)l*768*2048, 2048, 768, MR, 768, 2048,
         fb2 + l*768, x, x, nullptr, 1.f, 0);
  }
  k_ln<true><<<MR, 256, 0, stream>>>(x, eng, enb, ctx);

  // ----- precompute -----
  k_transpose_f<<<dim3(3072/32, 768/32), 256, 0, stream>>>(V0, V0t, 768, 3072);
  k_transpose_f<<<dim3(768/32, 768/32), 256, 0, stream>>>(cw2, cw2t, 768, 768);
  k_transpose_split<<<dim3(768/32, 3072/32), 256, 0, stream>>>(V1, V1th, V1tl, 3072, 768);
  k_split<<<(768*768 + 255)/256, 256, 0, stream>>>(cw1, Wc1h, Wc1l, 768*768);
  k_split<<<(768*768 + 255)/256, 256, 0, stream>>>(cw2, WDh, WDl, 768*768);
  k_bdg<<<3, 256, 0, stream>>>(gw, cb2, bdg);
  // WAf[0:3072][k] = ALPHA * (R@V0)[k][n]
  gemmT(stream, true, V0t, 768, Rm, 768, 768, 3072, 768, 768, nullptr, nullptr,
       WAf, nullptr, ALPHAF, 0);
  // WAf[3072+j][k] = ALPHA * (R@temp_w^T)[k][j]
  gemmT(stream, true, tw, 768, Rm, 768, 768, 768, 768, 768, nullptr, nullptr,
       WAf + (size_t)3072*768, nullptr, ALPHAF, 0);
  // ctxV0 = ctx@V0 + b0
  gemmT(stream, true, ctx, 768, V0t, 768, 3072, MR, 3072, 768, b0, nullptr,
       ctxV0, nullptr, 1.f, 0);
  // gctx = ctx @ gate_w[:, :768]^T
  gemmT(stream, true, ctx, 768, gw, 1536, 768, MR, 768, 768, nullptr, nullptr,
       gctx, nullptr, 1.f, 0);
  // WDg[g][i] = (gate_w[:,768:] @ cp_w2)[g][i]
  gemmT(stream, true, gw + 768, 1536, cw2t, 768, 768, 768, 768, 768, nullptr, nullptr,
       WDg, nullptr, 1.f, 0);
  k_split<<<((3840*768) + 255)/256, 256, 0, stream>>>(WAf, WAh, WAl, 3840*768);
  k_split<<<(768*768 + 255)/256, 256, 0, stream>>>(WDg, WDh + (size_t)768*768, WDl + (size_t)768*768, 768*768);

  // ----- recurrence -----
  k_init<<<1, 64, 0, stream>>>(cnt);
  k_scan<<<NWG, 256, 0, stream>>>(WAh, WAl, V1th, V1tl, Wc1h, Wc1l, WDh, WDl,
      ctxV0, gctx, ctx, b1, cb1, cb2, bdg, gb, og, ob, hall,
      hbh, hbl, h1h, h1l, c1, c1h, c1l, gcah, gcal, cf, gpre, tfs, cnt);

  // ----- lm head (plain bf16) -----
  gemmT(stream, false, hall, 768, lmw, 768, 50257, MR, 50257, 768, nullptr, nullptr,
       out, nullptr, 1.f, 0);
}

// Round 3
// 5629.099 us; speedup vs baseline: 1.7085x; 1.7085x over previous
//
#include <hip/hip_runtime.h>
#include <math.h>

typedef __bf16 bf16;
typedef __bf16 bf16x8 __attribute__((ext_vector_type(8)));
typedef __bf16 bf16x4 __attribute__((ext_vector_type(4)));
typedef float  f32x4  __attribute__((ext_vector_type(4)));

#define TT 64
#define DD 768
#define MR 1024      // B*T = 16*64
#define ALPHAF 0.4f
#define NWG 64       // persistent scan workgroups

__device__ __forceinline__ float geluf(float x){
  return 0.5f*x*(1.0f + erff(x*0.70710678118654752f));
}
__device__ __forceinline__ void split2(float v, bf16* hi, bf16* lo){
  bf16 h = (bf16)v; *hi = h; *lo = (bf16)(v - (float)h);
}

// ---------------- embedding ----------------
__global__ __launch_bounds__(256) void k_embed(const int* __restrict__ tok,
    const float* __restrict__ emb, const float* __restrict__ pos, float* __restrict__ x){
  int m = blockIdx.x; int t = m & 63; int id = tok[m];
  const float* e = emb + (size_t)id*DD;
  const float* p = pos + (size_t)t*DD;
  float* xr = x + (size_t)m*DD;
  for (int j = threadIdx.x; j < DD; j += 256) xr[j] = e[j] + p[j];
}

// ---------------- layernorm (+optional l2norm) ----------------
template<bool L2N>
__global__ __launch_bounds__(256) void k_ln(const float* __restrict__ in,
    const float* __restrict__ g, const float* __restrict__ b, float* __restrict__ out){
  __shared__ float red[8];
  int m = blockIdx.x, tid = threadIdx.x, lane = tid & 63, wid = tid >> 6;
  const float* x = in + (size_t)m*DD;
  float v[3]; float s = 0.f, ss = 0.f;
  #pragma unroll
  for (int j = 0; j < 3; j++){ float t0 = x[tid + j*256]; v[j] = t0; s += t0; ss += t0*t0; }
  #pragma unroll
  for (int o = 1; o < 64; o <<= 1){ s += __shfl_xor(s, o); ss += __shfl_xor(ss, o); }
  if (lane == 0){ red[wid] = s; red[4+wid] = ss; }
  __syncthreads();
  s  = red[0]+red[1]+red[2]+red[3];
  ss = red[4]+red[5]+red[6]+red[7];
  float mean = s*(1.f/768.f);
  float var  = ss*(1.f/768.f) - mean*mean;
  float rstd = rsqrtf(var + 1e-5f);
  float y[3];
  #pragma unroll
  for (int j = 0; j < 3; j++){ int n = tid + j*256; y[j] = (v[j]-mean)*rstd*g[n] + b[n]; }
  if (L2N){
    float n2 = y[0]*y[0] + y[1]*y[1] + y[2]*y[2];
    #pragma unroll
    for (int o = 1; o < 64; o <<= 1) n2 += __shfl_xor(n2, o);
    __syncthreads();
    if (lane == 0) red[wid] = n2;
    __syncthreads();
    n2 = red[0]+red[1]+red[2]+red[3];
    float inv = 1.f / fmaxf(sqrtf(n2), 1e-12f);
    y[0] *= inv; y[1] *= inv; y[2] *= inv;
  }
  float* o_ = out + (size_t)m*DD;
  #pragma unroll
  for (int j = 0; j < 3; j++) o_[tid + j*256] = y[j];
}

// ---------------- attention (one WG per (b,h)) ----------------
__global__ __launch_bounds__(256) void k_attn(const float* __restrict__ qkv, float* __restrict__ o){
  __shared__ float kv[64][96];
  __shared__ float sm[64][68];
  int bh = blockIdx.x; int b = bh >> 3, h = bh & 7;
  int tid = threadIdx.x;
  const float* base = qkv + (size_t)b*64*2304 + h*96;
  for (int idx = tid; idx < 64*96; idx += 256){ int i = idx/96, d = idx - i*96;
    kv[i][d] = base[(size_t)i*2304 + 768 + d]; }
  __syncthreads();
  {
    int i = tid >> 2;
    const float* q = base + (size_t)i*2304;
    int j0 = (tid & 3)*16;
    for (int jj = 0; jj < 16; jj++){
      int j = j0 + jj;
      float sv = -1e30f;
      if (j <= i){ float acc = 0.f;
        for (int d = 0; d < 96; d++) acc += q[d]*kv[j][d];
        sv = acc*0.10206207261596576f; }
      sm[i][j] = sv;
    }
  }
  __syncthreads();
  for (int idx = tid; idx < 64*96; idx += 256){ int i = idx/96, d = idx - i*96;
    kv[i][d] = base[(size_t)i*2304 + 1536 + d]; }
  if (tid < 64){
    int i = tid;
    float mx = -1e30f;
    for (int j = 0; j <= i; j++) mx = fmaxf(mx, sm[i][j]);
    float sum = 0.f;
    for (int j = 0; j <= i; j++){ float e = expf(sm[i][j]-mx); sm[i][j] = e; sum += e; }
    float inv = 1.f/sum;
    for (int j = 0; j <= i; j++) sm[i][j] *= inv;
  }
  __syncthreads();
  for (int idx = tid; idx < 64*96; idx += 256){
    int i = idx/96, d = idx - i*96;
    float acc = 0.f;
    for (int j = 0; j <= i; j++) acc += sm[i][j]*kv[j][d];
    o[(size_t)(b*64+i)*768 + h*96 + d] = acc;
  }
}

// ---------------- generic MFMA GEMM: out[M,N] = act(scale*A[M,K]@B[N,K]^T + bias) + res ----------------
template<bool SPLIT>
__global__ __launch_bounds__(256) void k_gemm(
    const float* __restrict__ A, int lda,
    const float* __restrict__ Bw, int ldb, int nrb,
    int M, int N, int K,
    const float* __restrict__ bias, const float* __restrict__ res,
    float* __restrict__ outF, bf16* __restrict__ outB,
    float scale, int act)
{
  __shared__ bf16 Ash[128][40];
  __shared__ bf16 Bsh[128][40];
  __shared__ bf16 Asl[SPLIT?128:1][40];
  __shared__ bf16 Bsl[SPLIT?128:1][40];
  int tid = threadIdx.x;
  int m0 = blockIdx.y*128, n0 = blockIdx.x*128;
  int lane = tid & 63, wid = tid >> 6;
  int wr = (wid >> 1)*64, wc = (wid & 1)*64;
  int l15 = lane & 15, kb = lane >> 4;
  f32x4 acc[4][4];
  #pragma unroll
  for (int i = 0; i < 4; i++)
    #pragma unroll
    for (int j = 0; j < 4; j++){ f32x4 z = {0.f,0.f,0.f,0.f}; acc[i][j] = z; }
  int rA = tid >> 3;          // 0..31
  int k4 = (tid & 7)*4;       // 0..28
  for (int kk = 0; kk < K; kk += 32){
    #pragma unroll
    for (int it = 0; it < 4; ++it){
      int r = it*32 + rA;
      float4 va = *(const float4*)(A + (size_t)(m0+r)*lda + kk + k4);
      bf16 h0,h1_,h2,h3,l0,l1,l2,l3;
      split2(va.x,&h0,&l0); split2(va.y,&h1_,&l1); split2(va.z,&h2,&l2); split2(va.w,&h3,&l3);
      *(bf16x4*)(&Ash[r][k4]) = (bf16x4){h0,h1_,h2,h3};
      if (SPLIT) *(bf16x4*)(&Asl[r][k4]) = (bf16x4){l0,l1,l2,l3};
      int rB = n0 + r;
      float4 vb;
      if (rB < nrb) vb = *(const float4*)(Bw + (size_t)rB*ldb + kk + k4);
      else { vb.x = 0.f; vb.y = 0.f; vb.z = 0.f; vb.w = 0.f; }
      split2(vb.x,&h0,&l0); split2(vb.y,&h1_,&l1); split2(vb.z,&h2,&l2); split2(vb.w,&h3,&l3);
      *(bf16x4*)(&Bsh[r][k4]) = (bf16x4){h0,h1_,h2,h3};
      if (SPLIT) *(bf16x4*)(&Bsl[r][k4]) = (bf16x4){l0,l1,l2,l3};
    }
    __syncthreads();
    bf16x8 ah[4], bh[4], al[4], bl[4];
    #pragma unroll
    for (int i = 0; i < 4; i++){ ah[i] = *(const bf16x8*)(&Ash[wr + i*16 + l15][kb*8]);
      if (SPLIT) al[i] = *(const bf16x8*)(&Asl[wr + i*16 + l15][kb*8]); }
    #pragma unroll
    for (int j = 0; j < 4; j++){ bh[j] = *(const bf16x8*)(&Bsh[wc + j*16 + l15][kb*8]);
      if (SPLIT) bl[j] = *(const bf16x8*)(&Bsl[wc + j*16 + l15][kb*8]); }
    #pragma unroll
    for (int i = 0; i < 4; i++)
      #pragma unroll
      for (int j = 0; j < 4; j++){
        acc[i][j] = __builtin_amdgcn_mfma_f32_16x16x32_bf16(ah[i], bh[j], acc[i][j], 0, 0, 0);
        if (SPLIT){
          acc[i][j] = __builtin_amdgcn_mfma_f32_16x16x32_bf16(ah[i], bl[j], acc[i][j], 0, 0, 0);
          acc[i][j] = __builtin_amdgcn_mfma_f32_16x16x32_bf16(al[i], bh[j], acc[i][j], 0, 0, 0);
        }
      }
    __syncthreads();
  }
  #pragma unroll
  for (int i = 0; i < 4; i++){
    #pragma unroll
    for (int j = 0; j < 4; j++){
      #pragma unroll
      for (int r = 0; r < 4; r++){
        int m = m0 + wr + i*16 + kb*4 + r;
        int n = n0 + wc + j*16 + l15;
        if (n < N){
          float v = acc[i][j][r]*scale;
          if (bias) v += bias[n];
          if (act == 1) v = geluf(v);
          if (res) v += res[(size_t)m*N + n];
          size_t off = (size_t)m*N + n;
          if (outF) outF[off] = v;
          if (outB) outB[off] = (bf16)v;
        }
      }
    }
  }
}

// ---------------- transpose / split helpers ----------------
__global__ __launch_bounds__(256) void k_transpose_f(const float* __restrict__ in, float* __restrict__ out, int R, int C){
  __shared__ float tile[32][33];
  int r0 = blockIdx.y*32, c0 = blockIdx.x*32;
  int tx = threadIdx.x & 31, ty = threadIdx.x >> 5;
  #pragma unroll
  for (int i = 0; i < 32; i += 8) tile[ty+i][tx] = in[(size_t)(r0+ty+i)*C + (c0+tx)];
  __syncthreads();
  #pragma unroll
  for (int i = 0; i < 32; i += 8) out[(size_t)(c0+ty+i)*R + (r0+tx)] = tile[tx][ty+i];
}

__global__ __launch_bounds__(256) void k_transpose_split(const float* __restrict__ in,
    bf16* __restrict__ hi, bf16* __restrict__ lo, int R, int C){
  __shared__ float tile[32][33];
  int r0 = blockIdx.y*32, c0 = blockIdx.x*32;
  int tx = threadIdx.x & 31, ty = threadIdx.x >> 5;
  #pragma unroll
  for (int i = 0; i < 32; i += 8) tile[ty+i][tx] = in[(size_t)(r0+ty+i)*C + (c0+tx)];
  __syncthreads();
  #pragma unroll
  for (int i = 0; i < 32; i += 8){
    size_t off = (size_t)(c0+ty+i)*R + (r0+tx);
    split2(tile[tx][ty+i], hi+off, lo+off);
  }
}

__global__ __launch_bounds__(256) void k_split(const float* __restrict__ in,
    bf16* __restrict__ hi, bf16* __restrict__ lo, int n){
  int i = blockIdx.x*256 + threadIdx.x;
  if (i < n) split2(in[i], hi+i, lo+i);
}

__global__ __launch_bounds__(256) void k_bdg(const float* __restrict__ gw, const float* __restrict__ cpb2, float* __restrict__ bdg){
  int g = blockIdx.x*256 + threadIdx.x;
  if (g < 768){
    const float* row = gw + (size_t)g*1536 + 768;
    float s = 0.f;
    for (int j = 0; j < 768; j++) s += cpb2[j]*row[j];
    bdg[g] = s;
  }
}

__global__ void k_init(int* flags){
  for (int i = threadIdx.x; i < NWG*32; i += 256) flags[i] = 0;
}

// ---------------- persistent scan ----------------
template<int KK>
__device__ __forceinline__ f32x4 dot16s(const bf16* __restrict__ ah, const bf16* __restrict__ al,
                                        const bf16* __restrict__ bh, const bf16* __restrict__ bl){
  f32x4 a0 = {0.f,0.f,0.f,0.f}, a1 = {0.f,0.f,0.f,0.f};
  #pragma unroll
  for (int kk = 0; kk < KK; kk += 32){
    bf16x8 vah = *(const bf16x8*)(ah+kk), val_ = *(const bf16x8*)(al+kk);
    bf16x8 vbh = *(const bf16x8*)(bh+kk), vbl  = *(const bf16x8*)(bl+kk);
    a0 = __builtin_amdgcn_mfma_f32_16x16x32_bf16(vah, vbh, a0, 0,0,0);
    a1 = __builtin_amdgcn_mfma_f32_16x16x32_bf16(vah, vbl, a1, 0,0,0);
    a1 = __builtin_amdgcn_mfma_f32_16x16x32_bf16(val_, vbh, a1, 0,0,0);
  }
  return a0 + a1;
}

// flag-array barrier: WG bid stores epoch to its own cacheline; wave 0's lane l
// polls WG l's flag; ballot over 64 lanes detects all-arrived in one RTT.
__device__ __forceinline__ void gbar(int* flags, int ep, int bid){
  __syncthreads();
  if (threadIdx.x < 64){
    if (threadIdx.x == 0){
      __threadfence();
      __hip_atomic_store(flags + bid*32, ep, __ATOMIC_RELEASE, __HIP_MEMORY_SCOPE_AGENT);
    }
    while (true){
      int v = __hip_atomic_load(flags + threadIdx.x*32, __ATOMIC_RELAXED, __HIP_MEMORY_SCOPE_AGENT);
      if (__ballot(v >= ep) == ~0ull) break;
    }
    __threadfence();
  }
  __syncthreads();
}

__global__ __launch_bounds__(256, 1) void k_scan(
  const bf16* __restrict__ WAh, const bf16* __restrict__ WAl,
  const bf16* __restrict__ V1th, const bf16* __restrict__ V1tl,
  const bf16* __restrict__ Wc1h, const bf16* __restrict__ Wc1l,
  const bf16* __restrict__ WDh, const bf16* __restrict__ WDl,
  const float* __restrict__ ctxV0b, const float* __restrict__ gctx,
  const float* __restrict__ ctx,
  const float* __restrict__ b1, const float* __restrict__ cpb1,
  const float* __restrict__ cpb2, const float* __restrict__ bdg,
  const float* __restrict__ gateb, const float* __restrict__ outg, const float* __restrict__ outb,
  float* __restrict__ hall,
  bf16* __restrict__ hbh, bf16* __restrict__ hbl,
  bf16* __restrict__ h1h, bf16* __restrict__ h1l,
  bf16* __restrict__ c1h, bf16* __restrict__ c1l,
  bf16* __restrict__ gcah, bf16* __restrict__ gcal,
  float* __restrict__ cf, float* __restrict__ gpre,
  float* __restrict__ tfs, int* flags)
{
  __shared__ float red[8];
  __shared__ float redbuf[4][256];
  __shared__ float normp[4][16];
  const int tid = threadIdx.x, lane = tid & 63, wid = tid >> 6;
  const int bid = blockIdx.x;
  const int W = bid*4 + wid;
  const int l15 = lane & 15, kb = lane >> 4;
  int ep = 0;
  for (int t = 0; t < TT; ++t){
    // ---- stage A: [16,3840] = h @ [a*RV0 | a*R@temp_w^T]^T  (240 wave-units, full K=768)
    if (W < 240){
      int n0 = W*16;
      f32x4 a = {0.f,0.f,0.f,0.f};
      if (t > 0){
        size_t aoff = ((size_t)l15*TT + (t-1))*DD + kb*8;
        size_t boff = (size_t)(n0 + l15)*DD + kb*8;
        a = dot16s<768>(hbh + aoff, hbl + aoff, WAh + boff, WAl + boff);
      }
      #pragma unroll
      for (int r = 0; r < 4; r++){
        int m = kb*4 + r, n = n0 + l15;
        float v = a[r];
        if (n < 3072){
          float hv = geluf(v + ctxV0b[((size_t)m*TT + t)*3072 + n]);
          split2(hv, h1h + m*3072 + n, h1l + m*3072 + n);
        } else tfs[m*DD + (n - 3072)] = v;
      }
    }
    gbar(flags, ++ep, bid);
    // ---- stage B: c1 = gelu(h1 @ V1 + b1)  (48 WGs, K=3072 split 4 ways across waves)
    if (bid < 48){
      int n0 = bid*16;
      size_t aoff = (size_t)l15*3072 + wid*768 + kb*8;
      size_t boff = (size_t)(n0 + l15)*3072 + wid*768 + kb*8;
      f32x4 a = dot16s<768>(h1h + aoff, h1l + aoff, V1th + boff, V1tl + boff);
      *(f32x4*)&redbuf[wid][lane*4] = a;
    }
    __syncthreads();
    if (bid < 48 && wid == 0){
      f32x4 a = *(f32x4*)&redbuf[0][lane*4];
      #pragma unroll
      for (int q = 1; q < 4; q++) a += *(f32x4*)&redbuf[q][lane*4];
      int n0 = bid*16;
      #pragma unroll
      for (int r = 0; r < 4; r++){
        int m = kb*4 + r, n = n0 + l15;
        float v = geluf(a[r] + b1[n]);
        split2(v, c1h + m*DD + n, c1l + m*DD + n);
      }
    }
    gbar(flags, ++ep, bid);
    // ---- stage C: gca = gelu(l2norm(c1) @ cp_w1^T + cp_b1)  (48 WGs, K=768 split 4; sumsq fused)
    if (bid < 48){
      int n0 = bid*16;
      size_t aoff = (size_t)l15*DD + wid*192 + kb*8;
      size_t boff = (size_t)(n0 + l15)*DD + wid*192 + kb*8;
      f32x4 a0 = {0.f,0.f,0.f,0.f}, a1 = {0.f,0.f,0.f,0.f};
      float sq = 0.f;
      #pragma unroll
      for (int it = 0; it < 6; ++it){
        bf16x8 vah = *(const bf16x8*)(c1h + aoff + it*32);
        bf16x8 val_ = *(const bf16x8*)(c1l + aoff + it*32);
        bf16x8 vbh = *(const bf16x8*)(Wc1h + boff + it*32);
        bf16x8 vbl = *(const bf16x8*)(Wc1l + boff + it*32);
        a0 = __builtin_amdgcn_mfma_f32_16x16x32_bf16(vah, vbh, a0, 0,0,0);
        a1 = __builtin_amdgcn_mfma_f32_16x16x32_bf16(vah, vbl, a1, 0,0,0);
        a1 = __builtin_amdgcn_mfma_f32_16x16x32_bf16(val_, vbh, a1, 0,0,0);
        #pragma unroll
        for (int j = 0; j < 8; j++){
          float xv = (float)vah[j] + (float)val_[j];
          sq = fmaf(xv, xv, sq);
        }
      }
      a0 += a1;
      sq += __shfl_xor(sq, 16); sq += __shfl_xor(sq, 32);
      if (lane < 16) normp[wid][lane] = sq;
      *(f32x4*)&redbuf[wid][lane*4] = a0;
    }
    __syncthreads();
    if (bid < 48 && wid == 0){
      f32x4 a = *(f32x4*)&redbuf[0][lane*4];
      #pragma unroll
      for (int q = 1; q < 4; q++) a += *(f32x4*)&redbuf[q][lane*4];
      int n0 = bid*16;
      #pragma unroll
      for (int r = 0; r < 4; r++){
        int m = kb*4 + r, n = n0 + l15;
        float nm = normp[0][m] + normp[1][m] + normp[2][m] + normp[3][m];
        float inv = 1.f / fmaxf(sqrtf(nm), 1e-12f);
        float v = geluf(a[r]*inv + cpb1[n]);
        split2(v, gcah + m*DD + n, gcal + m*DD + n);
      }
    }
    gbar(flags, ++ep, bid);
    // ---- stage D: [cf | gate_pre_cf] = gca @ [cp_w2 | Wdg]^T  (96 units, K=768 split 2)
    if (bid < 48){
      int u = bid*2 + (wid >> 1);
      int n0 = u*16;
      size_t aoff = (size_t)l15*DD + (wid & 1)*384 + kb*8;
      size_t boff = (size_t)(n0 + l15)*DD + (wid & 1)*384 + kb*8;
      f32x4 a = dot16s<384>(gcah + aoff, gcal + aoff, WDh + boff, WDl + boff);
      *(f32x4*)&redbuf[wid][lane*4] = a;
    }
    __syncthreads();
    if (bid < 48 && (wid & 1) == 0){
      f32x4 a = *(f32x4*)&redbuf[wid][lane*4];
      a += *(f32x4*)&redbuf[wid+1][lane*4];
      int u = bid*2 + (wid >> 1);
      int n0 = u*16;
      #pragma unroll
      for (int r = 0; r < 4; r++){
        int m = kb*4 + r, n = n0 + l15;
        if (n < 768) cf[m*DD + n] = a[r] + cpb2[n];
        else         gpre[m*DD + (n - 768)] = a[r] + bdg[n - 768];
      }
    }
    gbar(flags, ++ep, bid);
    // ---- combine: gate, h_t = clip(LN(...))  (16 WGs)
    if (bid < 16){
      int m = bid;
      size_t bidx = ((size_t)m*TT + t)*DD;
      float vals[3]; float s = 0.f, ss = 0.f;
      #pragma unroll
      for (int j = 0; j < 3; j++){
        int n = tid + j*256;
        float gi = gctx[bidx + n] + gpre[m*DD + n] + gateb[n];
        float gate = 1.f/(1.f + expf(-gi));
        float val = gate*(cf[m*DD + n] + tfs[m*DD + n]) + (1.f - gate)*ctx[bidx + n];
        vals[j] = val; s += val; ss += val*val;
      }
      #pragma unroll
      for (int o = 1; o < 64; o <<= 1){ s += __shfl_xor(s, o); ss += __shfl_xor(ss, o); }
      if (lane == 0){ red[wid] = s; red[4+wid] = ss; }
      __syncthreads();
      s  = red[0]+red[1]+red[2]+red[3];
      ss = red[4]+red[5]+red[6]+red[7];
      float mean = s*(1.f/768.f), var = ss*(1.f/768.f) - mean*mean;
      float rstd = rsqrtf(var + 1e-5f);
      #pragma unroll
      for (int j = 0; j < 3; j++){
        int n = tid + j*256;
        float y = (vals[j]-mean)*rstd*outg[n] + outb[n];
        y = fminf(5.f, fmaxf(-5.f, y));
        hall[bidx + n] = y;
        split2(y, hbh + bidx + n, hbl + bidx + n);
      }
    }
    gbar(flags, ++ep, bid);
  }
}

// ---------------- host ----------------
static inline void gemmT(hipStream_t s, bool split, const float* A, int lda, const float* Bw, int ldb, int nrb,
                        int M, int N, int K, const float* bias, const float* res,
                        float* outF, bf16* outB, float scale, int act){
  dim3 g((N + 127)/128, M/128);
  if (split) k_gemm<true><<<g, 256, 0, s>>>(A, lda, Bw, ldb, nrb, M, N, K, bias, res, outF, outB, scale, act);
  else       k_gemm<false><<<g, 256, 0, s>>>(A, lda, Bw, ldb, nrb, M, N, K, bias, res, outF, outB, scale, act);
}

extern "C" void kernel_launch(void* const* d_in, const int* in_sizes, int n_in,
                              void* d_out, int out_size, void* d_ws, size_t ws_size,
                              hipStream_t stream)
{
  (void)in_sizes; (void)n_in; (void)out_size; (void)ws_size;
  const int*   tok = (const int*)d_in[0];
  const float* emb = (const float*)d_in[1];
  const float* pos = (const float*)d_in[2];
  const float* aiw = (const float*)d_in[3];
  const float* aib = (const float*)d_in[4];
  const float* aow = (const float*)d_in[5];
  const float* aob = (const float*)d_in[6];
  const float* fw1 = (const float*)d_in[7];
  const float* fb1 = (const float*)d_in[8];
  const float* fw2 = (const float*)d_in[9];
  const float* fb2 = (const float*)d_in[10];
  const float* n1g = (const float*)d_in[11];
  const float* n1b = (const float*)d_in[12];
  const float* n2g = (const float*)d_in[13];
  const float* n2b = (const float*)d_in[14];
  const float* eng = (const float*)d_in[15];
  const float* enb = (const float*)d_in[16];
  const float* V0  = (const float*)d_in[17];
  const float* b0  = (const float*)d_in[18];
  const float* V1  = (const float*)d_in[19];
  const float* b1  = (const float*)d_in[20];
  const float* cw1 = (const float*)d_in[21];
  const float* cb1 = (const float*)d_in[22];
  const float* cw2 = (const float*)d_in[23];
  const float* cb2 = (const float*)d_in[24];
  const float* gw  = (const float*)d_in[25];
  const float* gb  = (const float*)d_in[26];
  const float* tw  = (const float*)d_in[27];
  const float* Rm  = (const float*)d_in[28];
  const float* og  = (const float*)d_in[29];
  const float* ob  = (const float*)d_in[30];
  const float* lmw = (const float*)d_in[31];
  float* out = (float*)d_out;

  char* base = (char*)d_ws; size_t off = 0;
  auto alloc = [&](size_t bytes)->void*{
    off = (off + 255) & ~(size_t)255; void* p = base + off; off += bytes; return p; };

  float* x     = (float*)alloc((size_t)MR*DD*4);
  float* xn    = (float*)alloc((size_t)MR*DD*4);
  float* qkv   = (float*)alloc((size_t)MR*2304*4);
  float* o_    = (float*)alloc((size_t)MR*DD*4);
  float* mid   = (float*)alloc((size_t)MR*2048*4);
  float* ctx   = (float*)alloc((size_t)MR*DD*4);
  float* V0t   = (float*)alloc((size_t)3072*768*4);
  float* cw2t  = (float*)alloc((size_t)768*768*4);
  float* ctxV0 = (float*)alloc((size_t)MR*3072*4);
  float* gctx  = (float*)alloc((size_t)MR*DD*4);
  float* hall  = (float*)alloc((size_t)MR*DD*4);
  float* WAf   = (float*)alloc((size_t)3840*768*4);
  float* WDg   = (float*)alloc((size_t)768*768*4);
  float* bdg   = (float*)alloc(768*4);
  bf16*  WAh   = (bf16*)alloc((size_t)3840*768*2);
  bf16*  WAl   = (bf16*)alloc((size_t)3840*768*2);
  bf16*  V1th  = (bf16*)alloc((size_t)768*3072*2);
  bf16*  V1tl  = (bf16*)alloc((size_t)768*3072*2);
  bf16*  Wc1h  = (bf16*)alloc((size_t)768*768*2);
  bf16*  Wc1l  = (bf16*)alloc((size_t)768*768*2);
  bf16*  WDh   = (bf16*)alloc((size_t)1536*768*2);
  bf16*  WDl   = (bf16*)alloc((size_t)1536*768*2);
  bf16*  hbh   = (bf16*)alloc((size_t)MR*DD*2);
  bf16*  hbl   = (bf16*)alloc((size_t)MR*DD*2);
  bf16*  h1h   = (bf16*)alloc((size_t)16*3072*2);
  bf16*  h1l   = (bf16*)alloc((size_t)16*3072*2);
  bf16*  c1h   = (bf16*)alloc((size_t)16*768*2);
  bf16*  c1l   = (bf16*)alloc((size_t)16*768*2);
  bf16*  gcah  = (bf16*)alloc((size_t)16*768*2);
  bf16*  gcal  = (bf16*)alloc((size_t)16*768*2);
  float* cf    = (float*)alloc((size_t)16*768*4);
  float* gpre  = (float*)alloc((size_t)16*768*4);
  float* tfs   = (float*)alloc((size_t)16*768*4);
  int*   flags = (int*)alloc((size_t)NWG*32*4);

  // ----- encoder -----
  k_embed<<<MR, 256, 0, stream>>>(tok, emb, pos, x);
  for (int l = 0; l < 2; l++){
    k_ln<false><<<MR, 256, 0, stream>>>(x, n1g + l*768, n1b + l*768, xn);
    gemmT(stream, true, xn, 768, aiw + (size_t)l*2304*768, 768, 2304, MR, 2304, 768,
         aib + l*2304, nullptr, qkv, nullptr, 1.f, 0);
    k_attn<<<128, 256, 0, stream>>>(qkv, o_);
    gemmT(stream, true, o_, 768, aow + (size_t)l*768*768, 768, 768, MR, 768, 768,
         aob + l*768, x, x, nullptr, 1.f, 0);
    k_ln<false><<<MR, 256, 0, stream>>>(x, n2g + l*768, n2b + l*768, xn);
    gemmT(stream, true, xn, 768, fw1 + (size_t)l*2048*768, 768, 2048, MR, 2048, 768,
         fb1 + l*2048, nullptr, mid, nullptr, 1.f, 1);
    gemmT(stream, true, mid, 2048, fw2 + (size_t)l*768*2048, 2048, 768, MR, 768, 2048,
         fb2 + l*768, x, x, nullptr, 1.f, 0);
  }
  k_ln<true><<<MR, 256, 0, stream>>>(x, eng, enb, ctx);

  // ----- precompute -----
  k_transpose_f<<<dim3(3072/32, 768/32), 256, 0, stream>>>(V0, V0t, 768, 3072);
  k_transpose_f<<<dim3(768/32, 768/32), 256, 0, stream>>>(cw2, cw2t, 768, 768);
  k_transpose_split<<<dim3(768/32, 3072/32), 256, 0, stream>>>(V1, V1th, V1tl, 3072, 768);
  k_split<<<(768*768 + 255)/256, 256, 0, stream>>>(cw1, Wc1h, Wc1l, 768*768);
  k_split<<<(768*768 + 255)/256, 256, 0, stream>>>(cw2, WDh, WDl, 768*768);
  k_bdg<<<3, 256, 0, stream>>>(gw, cb2, bdg);
  gemmT(stream, true, V0t, 768, Rm, 768, 768, 3072, 768, 768, nullptr, nullptr,
       WAf, nullptr, ALPHAF, 0);
  gemmT(stream, true, tw, 768, Rm, 768, 768, 768, 768, 768, nullptr, nullptr,
       WAf + (size_t)3072*768, nullptr, ALPHAF, 0);
  gemmT(stream, true, ctx, 768, V0t, 768, 3072, MR, 3072, 768, b0, nullptr,
       ctxV0, nullptr, 1.f, 0);
  gemmT(stream, true, ctx, 768, gw, 1536, 768, MR, 768, 768, nullptr, nullptr,
       gctx, nullptr, 1.f, 0);
  gemmT(stream, true, gw + 768, 1536, cw2t, 768, 768, 768, 768, 768, nullptr, nullptr,
       WDg, nullptr, 1.f, 0);
  k_split<<<((3840*768) + 255)/256, 256, 0, stream>>>(WAf, WAh, WAl, 3840*768);
  k_split<<<(768*768 + 255)/256, 256, 0, stream>>>(WDg, WDh + (size_t)768*768, WDl + (size_t)768*768, 768*768);

  // ----- recurrence -----
  k_init<<<1, 256, 0, stream>>>(flags);
  k_scan<<<NWG, 256, 0, stream>>>(WAh, WAl, V1th, V1tl, Wc1h, Wc1l, WDh, WDl,
      ctxV0, gctx, ctx, b1, cb1, cb2, bdg, gb, og, ob, hall,
      hbh, hbl, h1h, h1l, c1h, c1l, gcah, gcal, cf, gpre, tfs, flags);

  // ----- lm head (plain bf16) -----
  gemmT(stream, false, hall, 768, lmw, 768, 50257, MR, 50257, 768, nullptr, nullptr,
       out, nullptr, 1.f, 0);
}